// Round 1
// baseline (1771.843 us; speedup 1.0000x reference)
//
#include <hip/hip_runtime.h>
#include <hip/hip_bf16.h>
#include <stdint.h>

#define SQ 2048
#define DH 64
#define NB 2
#define NH 16
#define NHK 4
#define GQ 4            // NH / NHK
#define BM 64           // q rows per block
#define BN 64           // kv rows per tile
#define ROWS_PER_WAVE 16
#define SPECIAL_START 2040   // SPECIAL_SEQ - NUM_SPECIAL
#define QSCALE 0.125f        // d^-0.5
#define CLAMP 50.0f

// rotations[0][32] == 0.0f exactly (row 0 of freqs is all zeros).
// If storage is fp32, 32-bit word #32 is that zero. If storage is bf16,
// word #32 covers elements 64,65 = rotations[1][0..1] = (1.0, ~0.75) != 0.
__global__ void detect_dtype_kernel(const uint32_t* __restrict__ rot_words,
                                    int* __restrict__ flag) {
    if (threadIdx.x == 0) *flag = (rot_words[32] != 0u) ? 1 : 0;
}

__device__ __forceinline__ float ldf(const void* p, size_t i, int bf) {
    if (bf) return __bfloat162float(((const __hip_bfloat16*)p)[i]);
    return ((const float*)p)[i];
}

__global__ __launch_bounds__(256, 2)
void attn_kernel(const void* __restrict__ qg, const void* __restrict__ kg,
                 const void* __restrict__ vg, const void* __restrict__ rotg,
                 void* __restrict__ outg, const int* __restrict__ flagp) {
    const int bf = *flagp;                 // wave-uniform
    const int qt = blockIdx.x;             // 0..31 q tile
    const int bh = blockIdx.y;             // 0..31 (= b*NH + h)
    const int b  = bh / NH;
    const int h  = bh % NH;
    const int kvh = h / GQ;
    const int qs = qt * BM;

    const int tid  = threadIdx.x;
    const int wave = tid >> 6;
    const int lane = tid & 63;
    const int r0   = wave * ROWS_PER_WAVE;

    // stride 68 floats: float4 reads land 8-per-bank (the b128 floor) - no extra conflicts
    __shared__ __align__(16) float Qs[BM][DH + 4];
    __shared__ __align__(16) float Ks[BN][DH + 4];
    __shared__ __align__(16) float Vs[BN][DH + 4];
    __shared__ __align__(16) float Ps[BM][BN + 4];

    const size_t qbase  = ((size_t)bh * SQ + qs) * DH;
    const size_t kvbase = ((size_t)(b * NHK + kvh) * SQ) * DH;

    // ---- load Q tile with RoPE ----
    for (int idx = tid; idx < BM * DH; idx += 256) {
        int r = idx >> 6, c = idx & 63;
        int srow = qs + r;
        float x  = ldf(qg, qbase + (size_t)r * DH + c, bf);
        int pc   = (c < 32) ? c + 32 : c - 32;
        float xp = ldf(qg, qbase + (size_t)r * DH + pc, bf);
        float rv = ldf(rotg, (size_t)srow * DH + c, bf);
        float sn = sinf(rv), cs = cosf(rv);
        float rh = (c < 32) ? -xp : xp;
        Qs[r][c] = x * cs + rh * sn;
    }

    float o[ROWS_PER_WAVE], m[ROWS_PER_WAVE], l[ROWS_PER_WAVE];
#pragma unroll
    for (int r = 0; r < ROWS_PER_WAVE; r++) { o[r] = 0.f; m[r] = -1e30f; l[r] = 0.f; }

    // block-causal: all kv tiles up through this q-tile's 256-block are FULLY allowed
    const int nkt = (qs / 256 + 1) * 4;

    for (int kt = 0; kt < nkt; kt++) {
        __syncthreads();   // previous iteration's Ks/Vs reads done
        // ---- load K (RoPE) + V tile ----
        for (int idx = tid; idx < BN * DH; idx += 256) {
            int r = idx >> 6, c = idx & 63;
            int srow = kt * BN + r;
            size_t base = kvbase + (size_t)srow * DH;
            float x  = ldf(kg, base + c, bf);
            int pc   = (c < 32) ? c + 32 : c - 32;
            float xp = ldf(kg, base + pc, bf);
            float rv = ldf(rotg, (size_t)srow * DH + c, bf);
            float sn = sinf(rv), cs = cosf(rv);
            float rh = (c < 32) ? -xp : xp;
            Ks[r][c] = x * cs + rh * sn;
            Vs[r][c] = ldf(vg, base + c, bf);
        }
        __syncthreads();

        // ---- QK^T: lane = key j in tile; acc[r] over 16 rows ----
        float acc[ROWS_PER_WAVE];
#pragma unroll
        for (int r = 0; r < ROWS_PER_WAVE; r++) acc[r] = 0.f;
        const float4* kp = (const float4*)&Ks[lane][0];
#pragma unroll
        for (int d4 = 0; d4 < DH / 4; d4++) {
            float4 kk = kp[d4];
#pragma unroll
            for (int r = 0; r < ROWS_PER_WAVE; r++) {
                const float4 qq = *(const float4*)&Qs[r0 + r][d4 * 4];
                acc[r] += qq.x * kk.x + qq.y * kk.y + qq.z * kk.z + qq.w * kk.w;
            }
        }

        const int  kj = kt * BN + lane;
        const bool kSpecial = (kj >= SPECIAL_START);  // only possible in kt==31
        float alpha[ROWS_PER_WAVE];
#pragma unroll
        for (int r = 0; r < ROWS_PER_WAVE; r++) {
            float sc = acc[r] * QSCALE;
            // 50*tanh(sc/50) via exp identity (cheap, accurate for |sc|<~6 here)
            float t = __expf(sc * (2.0f / CLAMP));
            sc = CLAMP * ((t - 1.0f) / (t + 1.0f));
            int qi = qs + r0 + r;
            if (kSpecial && (qi < SPECIAL_START)) sc = -1e30f;
            // wave-wide max
            float wm = sc;
#pragma unroll
            for (int off = 32; off; off >>= 1) wm = fmaxf(wm, __shfl_xor(wm, off, 64));
            float mnew = fmaxf(m[r], wm);
            float p = __expf(sc - mnew);
            float psum = p;
#pragma unroll
            for (int off = 32; off; off >>= 1) psum += __shfl_xor(psum, off, 64);
            float a = __expf(m[r] - mnew);
            l[r] = l[r] * a + psum;
            m[r] = mnew;
            alpha[r] = a;
            Ps[r0 + r][lane] = p;   // rows owned by this wave only
        }

        // ---- PV: lane = head-dim col; o[r] += P[row][:] . V[:][lane] ----
#pragma unroll
        for (int r = 0; r < ROWS_PER_WAVE; r++) o[r] *= alpha[r];
#pragma unroll
        for (int j4 = 0; j4 < BN / 4; j4++) {
            float v0 = Vs[j4 * 4 + 0][lane];
            float v1 = Vs[j4 * 4 + 1][lane];
            float v2 = Vs[j4 * 4 + 2][lane];
            float v3 = Vs[j4 * 4 + 3][lane];
#pragma unroll
            for (int r = 0; r < ROWS_PER_WAVE; r++) {
                float4 p4 = *(const float4*)&Ps[r0 + r][j4 * 4];
                o[r] += p4.x * v0 + p4.y * v1 + p4.z * v2 + p4.w * v3;
            }
        }
    }

    // ---- epilogue ----
#pragma unroll
    for (int r = 0; r < ROWS_PER_WAVE; r++) {
        int row = qs + r0 + r;
        float val = o[r] / l[r];
        size_t oi = ((size_t)bh * SQ + row) * DH + lane;
        if (bf) ((__hip_bfloat16*)outg)[oi] = __float2bfloat16(val);
        else    ((float*)outg)[oi] = val;
    }
}

extern "C" void kernel_launch(void* const* d_in, const int* in_sizes, int n_in,
                              void* d_out, int out_size, void* d_ws, size_t ws_size,
                              hipStream_t stream) {
    const void* q   = d_in[0];
    const void* k   = d_in[1];
    const void* v   = d_in[2];
    const void* rot = d_in[3];
    int* flag = (int*)d_ws;

    hipLaunchKernelGGL(detect_dtype_kernel, dim3(1), dim3(64), 0, stream,
                       (const uint32_t*)rot, flag);

    dim3 grid(SQ / BM, NB * NH);
    hipLaunchKernelGGL(attn_kernel, grid, dim3(256), 0, stream,
                       q, k, v, rot, d_out, flag);
}

// Round 5
// 253.212 us; speedup vs baseline: 6.9975x; 6.9975x over previous
//
#include <hip/hip_runtime.h>
#include <stdint.h>

typedef unsigned short u16;
typedef short s16x8 __attribute__((ext_vector_type(8)));
typedef float f32x4 __attribute__((ext_vector_type(4)));

#define SQ 2048
#define DH 64
#define BM 128
#define BN 64
#define STR 72             // LDS row stride in shorts (144 B, 16B-multiple)
#define SPECIAL_START 2040 // SPECIAL_SEQ - NUM_SPECIAL

union U8 { s16x8 v; short e[8]; };
union F4 { f32x4 v; float e[4]; };

__device__ __forceinline__ u16 f2bf(float x) {  // round-to-nearest-even
    uint32_t u = __float_as_uint(x);
    return (u16)((u + 0x7fffu + ((u >> 16) & 1u)) >> 16);
}

__global__ void sincos_kernel(const float* __restrict__ rot, float2* __restrict__ tab) {
    int i = blockIdx.x * 256 + threadIdx.x;
    if (i >= SQ * DH) return;
    float s, c;
    sincosf(rot[i], &s, &c);   // precise: rot reaches ~2047 rad
    tab[i] = make_float2(c, s);
}

__device__ __forceinline__ void getcs(const float2* tab, int use_tab,
                                      const float* rotg, int srow, int c,
                                      float& cs, float& sn) {
    if (use_tab) { float2 t = tab[(size_t)srow * DH + c]; cs = t.x; sn = t.y; }
    else          { sincosf(rotg[(size_t)srow * DH + c], &sn, &cs); }
}

// S^T = K.Q^T via mfma(A=K, B=Q)  -> C layout: col(lane&15)=q, row(quad*4+reg)=kv
// O^T = V^T.P via mfma(A=V^T, B=P) -> C layout: col(lane&15)=q, row(quad*4+reg)=d
__global__ __launch_bounds__(256)
void attn_kernel(const float* __restrict__ qg, const float* __restrict__ kg,
                 const float* __restrict__ vg, const float* __restrict__ rotg,
                 const float2* __restrict__ tab, int use_tab,
                 float* __restrict__ outg)
{
    const int x  = blockIdx.x;
    const int qt = (x & 1) ? (15 - (x >> 1)) : (x >> 1);  // pair heavy+light tiles
    const int bh = blockIdx.y;
    const int bb = bh >> 4, hh = bh & 15;
    const int kvh = hh >> 2;
    const int qs = qt * BM;

    const int tid = threadIdx.x;
    const int wv = tid >> 6, lane = tid & 63;
    const int l15 = lane & 15, quad = lane >> 4;

    __shared__ __align__(16) short Qs[BM * STR];
    __shared__ __align__(16) short Ks[BN * STR];
    __shared__ __align__(16) short Vs[BN * STR];   // natural [kv][d]
    __shared__ __align__(16) short Ps[BM * STR];   // P[q][kv]

    const size_t qbase  = ((size_t)bh * SQ + qs) * DH;
    const size_t kvbase = ((size_t)(bb * 4 + kvh) * SQ) * DH;

    // ---- stage Q with RoPE (fp32 in, bf16 to LDS; 2 threads/row) ----
    {
        int r = tid >> 1, c0 = (tid & 1) * 16;
        int srow = qs + r;
        const float* gq = qg + qbase + (size_t)r * DH;
        float lo[16], hi[16];
#pragma unroll
        for (int t = 0; t < 4; t++) {
            *(float4*)&lo[t * 4] = *(const float4*)(gq + c0 + t * 4);
            *(float4*)&hi[t * 4] = *(const float4*)(gq + c0 + 32 + t * 4);
        }
        U8 olo[2], ohi[2];
#pragma unroll
        for (int j = 0; j < 16; j++) {
            float cs, sn;
            getcs(tab, use_tab, rotg, srow, c0 + j, cs, sn);   // rot[c]==rot[c+32]
            olo[j >> 3].e[j & 7] = (short)f2bf(lo[j] * cs - hi[j] * sn);
            ohi[j >> 3].e[j & 7] = (short)f2bf(hi[j] * cs + lo[j] * sn);
        }
        *(s16x8*)&Qs[r * STR + c0]      = olo[0].v;
        *(s16x8*)&Qs[r * STR + c0 + 8]  = olo[1].v;
        *(s16x8*)&Qs[r * STR + c0 + 32] = ohi[0].v;
        *(s16x8*)&Qs[r * STR + c0 + 40] = ohi[1].v;
    }
    __syncthreads();

    // ---- preload Q fragments: B[n=q(lane&15)][k=quad*8+j] ----
    s16x8 qf[2][2];  // [nb][ks]
#pragma unroll
    for (int nb = 0; nb < 2; nb++)
#pragma unroll
        for (int ks = 0; ks < 2; ks++)
            qf[nb][ks] = *(const s16x8*)&Qs[(wv * 32 + nb * 16 + l15) * STR + ks * 32 + quad * 8];

    F4 oa[4][2];  // [mb(d 16-block)][nb(q 16-block)]
#pragma unroll
    for (int mb = 0; mb < 4; mb++)
#pragma unroll
        for (int nb = 0; nb < 2; nb++)
            oa[mb][nb].v = (f32x4){0.f, 0.f, 0.f, 0.f};
    float m2[2]   = {-1e30f, -1e30f};
    float lsum[2] = {0.f, 0.f};

    const int nkt = (qt / 2 + 1) * 4;   // kv tiles fully allowed by block-causal mask

    for (int kt = 0; kt < nkt; kt++) {
        __syncthreads();   // previous iteration's LDS reads done

        // ---- stage K with RoPE (4 threads/row) ----
        {
            int r = tid >> 2, c0 = (tid & 3) * 8;
            int srow = kt * BN + r;
            const float* gk = kg + kvbase + (size_t)srow * DH;
            float a[8], b[8];
            *(float4*)&a[0] = *(const float4*)(gk + c0);
            *(float4*)&a[4] = *(const float4*)(gk + c0 + 4);
            *(float4*)&b[0] = *(const float4*)(gk + c0 + 32);
            *(float4*)&b[4] = *(const float4*)(gk + c0 + 36);
            U8 o0, o1;
#pragma unroll
            for (int j = 0; j < 8; j++) {
                float cs, sn;
                getcs(tab, use_tab, rotg, srow, c0 + j, cs, sn);
                o0.e[j] = (short)f2bf(a[j] * cs - b[j] * sn);
                o1.e[j] = (short)f2bf(b[j] * cs + a[j] * sn);
            }
            *(s16x8*)&Ks[r * STR + c0]      = o0.v;
            *(s16x8*)&Ks[r * STR + c0 + 32] = o1.v;
        }
        // ---- stage V natural [kv][d] ----
        {
            int r = tid >> 2, c0 = (tid & 3) * 16;
            const float* gv = vg + kvbase + (size_t)(kt * BN + r) * DH;
            float vv[16];
#pragma unroll
            for (int t = 0; t < 4; t++)
                *(float4*)&vv[t * 4] = *(const float4*)(gv + c0 + t * 4);
            U8 w0, w1;
#pragma unroll
            for (int j = 0; j < 8; j++) {
                w0.e[j] = (short)f2bf(vv[j]);
                w1.e[j] = (short)f2bf(vv[8 + j]);
            }
            *(s16x8*)&Vs[r * STR + c0]     = w0.v;
            *(s16x8*)&Vs[r * STR + c0 + 8] = w1.v;
        }
        __syncthreads();

        // ---- QK^T: S^T[kv][q] ----
        F4 sa[4][2];
#pragma unroll
        for (int mb = 0; mb < 4; mb++) {
#pragma unroll
            for (int nb = 0; nb < 2; nb++) sa[mb][nb].v = (f32x4){0.f, 0.f, 0.f, 0.f};
#pragma unroll
            for (int ks = 0; ks < 2; ks++) {
                s16x8 kf = *(const s16x8*)&Ks[(mb * 16 + l15) * STR + ks * 32 + quad * 8];
#pragma unroll
                for (int nb = 0; nb < 2; nb++)
                    sa[mb][nb].v = __builtin_amdgcn_mfma_f32_16x16x32_bf16(kf, qf[nb][ks], sa[mb][nb].v, 0, 0, 0);
            }
        }

        // ---- softclamp + mask + online softmax (per-lane q = nb*16 + l15) ----
#pragma unroll
        for (int nb = 0; nb < 2; nb++) {
            const int qglob = qs + wv * 32 + nb * 16 + l15;
            float vm = -1e30f;
#pragma unroll
            for (int mb = 0; mb < 4; mb++)
#pragma unroll
                for (int c = 0; c < 4; c++) {
                    float xx = sa[mb][nb].e[c];
                    // 50*tanh(x*0.125/50) = 50 - 100/(e^(x*0.005)+1)
                    float t = __expf(xx * 0.005f);
                    float yy = 50.f - 100.f / (t + 1.f);
                    if (kt == 31) {   // only tile containing special keys
                        int kvglob = kt * BN + mb * 16 + quad * 4 + c;
                        if (kvglob >= SPECIAL_START && qglob < SPECIAL_START) yy = -1e30f;
                    }
                    sa[mb][nb].e[c] = yy;
                    vm = fmaxf(vm, yy);
                }
            vm = fmaxf(vm, __shfl_xor(vm, 16, 64));
            vm = fmaxf(vm, __shfl_xor(vm, 32, 64));
            float mnew = fmaxf(m2[nb], vm);
            float al = __expf(m2[nb] - mnew);
            m2[nb] = mnew;
            float ps = 0.f;
            short* prow = &Ps[(wv * 32 + nb * 16 + l15) * STR];
#pragma unroll
            for (int mb = 0; mb < 4; mb++) {
#pragma unroll
                for (int c = 0; c < 4; c++) {
                    float p = __expf(sa[mb][nb].e[c] - mnew);
                    ps += p;
                    prow[mb * 16 + quad * 4 + c] = (short)f2bf(p);
                }
            }
            ps += __shfl_xor(ps, 16, 64);
            ps += __shfl_xor(ps, 32, 64);
            lsum[nb] = lsum[nb] * al + ps;
#pragma unroll
            for (int mb = 0; mb < 4; mb++)
#pragma unroll
                for (int c = 0; c < 4; c++) oa[mb][nb].e[c] *= al;
        }

        __syncthreads();   // P writes visible before fragment reads

        // ---- PV: O^T[d][q] += V^T . P ----
#pragma unroll
        for (int ks = 0; ks < 2; ks++) {
            s16x8 pf[2];
#pragma unroll
            for (int nb = 0; nb < 2; nb++)
                pf[nb] = *(const s16x8*)&Ps[(wv * 32 + nb * 16 + l15) * STR + ks * 32 + quad * 8];
#pragma unroll
            for (int mb = 0; mb < 4; mb++) {
                U8 vf;  // A[m=d(lane&15)][k=kv(quad*8+j)] gathered from natural Vs
#pragma unroll
                for (int j = 0; j < 8; j++)
                    vf.e[j] = Vs[(ks * 32 + quad * 8 + j) * STR + mb * 16 + l15];
#pragma unroll
                for (int nb = 0; nb < 2; nb++)
                    oa[mb][nb].v = __builtin_amdgcn_mfma_f32_16x16x32_bf16(vf.v, pf[nb], oa[mb][nb].v, 0, 0, 0);
            }
        }
    }

    // ---- epilogue: O^T C-layout -> out[bh][q][d], fp32 stores ----
#pragma unroll
    for (int nb = 0; nb < 2; nb++) {
        float rl = 1.0f / lsum[nb];
        int qrow = qs + wv * 32 + nb * 16 + l15;
        float* orow = outg + ((size_t)bh * SQ + qrow) * DH;
#pragma unroll
        for (int mb = 0; mb < 4; mb++) {
            int d0 = mb * 16 + quad * 4;
            float4 o4 = make_float4(oa[mb][nb].e[0] * rl, oa[mb][nb].e[1] * rl,
                                    oa[mb][nb].e[2] * rl, oa[mb][nb].e[3] * rl);
            *(float4*)(orow + d0) = o4;
        }
    }
}

extern "C" void kernel_launch(void* const* d_in, const int* in_sizes, int n_in,
                              void* d_out, int out_size, void* d_ws, size_t ws_size,
                              hipStream_t stream) {
    const float* q   = (const float*)d_in[0];
    const float* k   = (const float*)d_in[1];
    const float* v   = (const float*)d_in[2];
    const float* rot = (const float*)d_in[3];
    float* out = (float*)d_out;
    float2* tab = (float2*)d_ws;
    const size_t tab_bytes = (size_t)SQ * DH * sizeof(float2);
    int use_tab = (ws_size >= tab_bytes) ? 1 : 0;

    if (use_tab) {
        hipLaunchKernelGGL(sincos_kernel, dim3((SQ * DH + 255) / 256), dim3(256), 0, stream,
                           rot, tab);
    }
    hipLaunchKernelGGL(attn_kernel, dim3(16, 32), dim3(256), 0, stream,
                       q, k, v, rot, tab, use_tab, out);
}

// Round 6
// 216.778 us; speedup vs baseline: 8.1735x; 1.1681x over previous
//
#include <hip/hip_runtime.h>
#include <stdint.h>

typedef unsigned short u16;
typedef short s16x8 __attribute__((ext_vector_type(8)));
typedef float f32x4 __attribute__((ext_vector_type(4)));

#define SQ 2048
#define DH 64
#define BM 64
#define BN 64
#define STR 72             // LDS row stride in shorts (144 B)
#define SPECIAL_START 2040
#define NBH 32             // b*h
#define NKV 8              // b*hk

union U8 { s16x8 v; short e[8]; };
union F4 { f32x4 v; float e[4]; };

__device__ __forceinline__ u16 f2bf(float x) {  // round-to-nearest-even
    uint32_t u = __float_as_uint(x);
    return (u16)((u + 0x7fffu + ((u >> 16) & 1u)) >> 16);
}

__global__ void sincos_kernel(const float* __restrict__ rot, float2* __restrict__ tab) {
    int i = blockIdx.x * 256 + threadIdx.x;
    if (i >= SQ * DH) return;
    float s, c;
    sincosf(rot[i], &s, &c);
    tab[i] = make_float2(c, s);
}

// Pre-rope Q,K (bf16) and transpose+swizzle V (bf16) into workspace.
// One wave per 64-element row.
#define RQ (NBH * SQ)
#define RK (NKV * SQ)
#define RV (NKV * SQ)
__global__ __launch_bounds__(256)
void prep_kernel(const float* __restrict__ qg, const float* __restrict__ kg,
                 const float* __restrict__ vg, const float2* __restrict__ tab,
                 u16* __restrict__ qp, u16* __restrict__ kp, u16* __restrict__ vp)
{
    const int lane = threadIdx.x & 63;
    const int R = blockIdx.x * 4 + (threadIdx.x >> 6);
    if (R < RQ + RK) {
        const int isQ = (R < RQ);
        const int r   = isQ ? R : R - RQ;
        const int s   = r & (SQ - 1);
        const float* src = (isQ ? qg : kg) + (size_t)r * DH + lane;
        u16*         dst = (isQ ? qp : kp) + (size_t)r * DH + lane;
        float x  = *src;
        float xp = __shfl_xor(x, 32, 64);
        float rh = (lane < 32) ? -xp : xp;
        float2 t = tab[s * DH + lane];
        *dst = f2bf(x * t.x + rh * t.y);
    } else if (R < RQ + RK + RV) {
        const int r   = R - RQ - RK;          // kv row
        const int bkv = r >> 11, s = r & (SQ - 1);
        const int kt = s >> 6, kv = s & 63, g = kv >> 3;
        const int d = lane;
        float x = vg[(size_t)r * DH + d];
        int col = ((g ^ (d >> 3)) << 3) | (kv & 7);
        vp[(((size_t)(bkv * 32 + kt) * 64 + d) << 6) + col] = f2bf(x);
    }
}

__device__ __forceinline__ void getcs(const float2* tab, int use_tab,
                                      const float* rotg, int srow, int c,
                                      float& cs, float& sn) {
    if (use_tab) { float2 t = tab[(size_t)srow * DH + c]; cs = t.x; sn = t.y; }
    else          { sincosf(rotg[(size_t)srow * DH + c], &sn, &cs); }
}

// S^T = K.Q^T via mfma(A=K,B=Q)   -> C: col(l15)=q, row(quad*4+c)=kv
// O^T = V^T.P via mfma(A=Vt,B=P)  -> C: col(l15)=q, row(quad*4+c)=d
__global__ __launch_bounds__(256, 4)
void attn_kernel(const float* __restrict__ qg, const float* __restrict__ kg,
                 const float* __restrict__ vg, const float* __restrict__ rotg,
                 const float2* __restrict__ tab, int use_tab, int use_pre,
                 const u16* __restrict__ qp, const u16* __restrict__ kp,
                 const u16* __restrict__ vp, float* __restrict__ outg)
{
    const int x  = blockIdx.x;
    const int qt = (x & 1) ? (31 - (x >> 1)) : (x >> 1);  // heavy+light pairing
    const int bh = blockIdx.y;
    const int bb = bh >> 4, hh = bh & 15;
    const int bkv = bb * 4 + (hh >> 2);
    const int qs = qt * BM;

    const int tid = threadIdx.x;
    const int wv = tid >> 6, lane = tid & 63;
    const int l15 = lane & 15, quad = lane >> 4;

    __shared__ __align__(16) short QPs[BM * STR];  // Q tile, then P[q][kv]
    __shared__ __align__(16) short Ks[BN * STR];
    __shared__ __align__(16) short Vt[DH * STR];   // [d][kv-swizzled]

    const size_t qbase  = ((size_t)bh * SQ + qs) * DH;
    const size_t kvbase = ((size_t)bkv * SQ) * DH;

    // ---- stage Q tile ----
    if (use_pre) {
        int r = tid >> 2, c0 = (tid & 3) * 16;
        const u16* src = qp + qbase + (size_t)r * DH + c0;
        *(s16x8*)&QPs[r * STR + c0]     = *(const s16x8*)src;
        *(s16x8*)&QPs[r * STR + c0 + 8] = *(const s16x8*)(src + 8);
    } else {
        int r = tid >> 2, c0 = (tid & 3) * 8;
        int srow = qs + r;
        const float* gq = qg + qbase + (size_t)r * DH;
        float a[8], b[8];
        *(float4*)&a[0] = *(const float4*)(gq + c0);
        *(float4*)&a[4] = *(const float4*)(gq + c0 + 4);
        *(float4*)&b[0] = *(const float4*)(gq + c0 + 32);
        *(float4*)&b[4] = *(const float4*)(gq + c0 + 36);
        U8 o0, o1;
#pragma unroll
        for (int j = 0; j < 8; j++) {
            float cs, sn;
            getcs(tab, use_tab, rotg, srow, c0 + j, cs, sn);
            o0.e[j] = (short)f2bf(a[j] * cs - b[j] * sn);
            o1.e[j] = (short)f2bf(b[j] * cs + a[j] * sn);
        }
        *(s16x8*)&QPs[r * STR + c0]      = o0.v;
        *(s16x8*)&QPs[r * STR + c0 + 32] = o1.v;
    }
    __syncthreads();

    // ---- preload Q fragments: B[n=q(l15)][k=quad*8+j] ----
    s16x8 qf[2];
#pragma unroll
    for (int ks = 0; ks < 2; ks++)
        qf[ks] = *(const s16x8*)&QPs[(wv * 16 + l15) * STR + ks * 32 + quad * 8];

    F4 oa[4];
#pragma unroll
    for (int mb = 0; mb < 4; mb++) oa[mb].v = (f32x4){0.f, 0.f, 0.f, 0.f};
    float m2 = -1e30f, lsum = 0.f;

    const int nkt = (qt / 4 + 1) * 4;   // block-causal: tiles fully allowed

    for (int kt = 0; kt < nkt; kt++) {
        __syncthreads();   // prev iteration's Ks/Vt reads done

        if (use_pre) {
            int r = tid >> 2, c0 = (tid & 3) * 16;
            const u16* srck = kp + kvbase + (size_t)(kt * BN + r) * DH + c0;
            *(s16x8*)&Ks[r * STR + c0]     = *(const s16x8*)srck;
            *(s16x8*)&Ks[r * STR + c0 + 8] = *(const s16x8*)(srck + 8);
            const u16* srcv = vp + (((size_t)(bkv * 32 + kt) * 64 + r) << 6) + c0;
            *(s16x8*)&Vt[r * STR + c0]     = *(const s16x8*)srcv;
            *(s16x8*)&Vt[r * STR + c0 + 8] = *(const s16x8*)(srcv + 8);
        } else {
            {   // K rope inline
                int r = tid >> 2, c0 = (tid & 3) * 8;
                int srow = kt * BN + r;
                const float* gk = kg + kvbase + (size_t)srow * DH;
                float a[8], b[8];
                *(float4*)&a[0] = *(const float4*)(gk + c0);
                *(float4*)&a[4] = *(const float4*)(gk + c0 + 4);
                *(float4*)&b[0] = *(const float4*)(gk + c0 + 32);
                *(float4*)&b[4] = *(const float4*)(gk + c0 + 36);
                U8 o0, o1;
#pragma unroll
                for (int j = 0; j < 8; j++) {
                    float cs, sn;
                    getcs(tab, use_tab, rotg, srow, c0 + j, cs, sn);
                    o0.e[j] = (short)f2bf(a[j] * cs - b[j] * sn);
                    o1.e[j] = (short)f2bf(b[j] * cs + a[j] * sn);
                }
                *(s16x8*)&Ks[r * STR + c0]      = o0.v;
                *(s16x8*)&Ks[r * STR + c0 + 32] = o1.v;
            }
            {   // V transpose+swizzle inline (scalar scatter, fallback only)
                int r = tid >> 2, c0 = (tid & 3) * 16;
                const float* gv = vg + kvbase + (size_t)(kt * BN + r) * DH;
                float vv[16];
#pragma unroll
                for (int t = 0; t < 4; t++)
                    *(float4*)&vv[t * 4] = *(const float4*)(gv + c0 + t * 4);
#pragma unroll
                for (int j = 0; j < 16; j++) {
                    int d = c0 + j;
                    int col = (((r >> 3) ^ (d >> 3)) << 3) | (r & 7);
                    Vt[d * STR + col] = (short)f2bf(vv[j]);
                }
            }
        }
        __syncthreads();

        // ---- QK^T: S^T[kv][q] ----
        F4 sa[4];
#pragma unroll
        for (int mb = 0; mb < 4; mb++) sa[mb].v = (f32x4){0.f, 0.f, 0.f, 0.f};
#pragma unroll
        for (int ks = 0; ks < 2; ks++) {
#pragma unroll
            for (int mb = 0; mb < 4; mb++) {
                s16x8 kf = *(const s16x8*)&Ks[(mb * 16 + l15) * STR + ks * 32 + quad * 8];
                sa[mb].v = __builtin_amdgcn_mfma_f32_16x16x32_bf16(kf, qf[ks], sa[mb].v, 0, 0, 0);
            }
        }

        // ---- softclamp + mask + online softmax (lane q = l15) ----
        const int qglob = qs + wv * 16 + l15;
        float vm = -1e30f;
#pragma unroll
        for (int mb = 0; mb < 4; mb++)
#pragma unroll
            for (int c = 0; c < 4; c++) {
                float xx = sa[mb].e[c];
                float t = __expf(xx * 0.005f);     // 50*tanh(x*0.125/50)
                float yy = 50.f - 100.f / (t + 1.f);
                if (kt == 31) {
                    int kvglob = kt * BN + mb * 16 + quad * 4 + c;
                    if (kvglob >= SPECIAL_START && qglob < SPECIAL_START) yy = -1e30f;
                }
                sa[mb].e[c] = yy;
                vm = fmaxf(vm, yy);
            }
        vm = fmaxf(vm, __shfl_xor(vm, 16, 64));
        vm = fmaxf(vm, __shfl_xor(vm, 32, 64));
        float mnew = fmaxf(m2, vm);
        float al = __expf(m2 - mnew);
        m2 = mnew;
        float ps = 0.f;
        short* prow = &QPs[(wv * 16 + l15) * STR];
#pragma unroll
        for (int mb = 0; mb < 4; mb++) {
            U8 pk;
#pragma unroll
            for (int c = 0; c < 4; c++) {
                float p = __expf(sa[mb].e[c] - mnew);
                ps += p;
                pk.e[c] = (short)f2bf(p);
            }
            // b64 store of 4 bf16 at kv = mb*16 + quad*4 (8B-aligned, conflict-free)
            *(short4*)&prow[mb * 16 + quad * 4] = make_short4(pk.e[0], pk.e[1], pk.e[2], pk.e[3]);
        }
        ps += __shfl_xor(ps, 16, 64);
        ps += __shfl_xor(ps, 32, 64);
        lsum = lsum * al + ps;
#pragma unroll
        for (int mb = 0; mb < 4; mb++)
#pragma unroll
            for (int c = 0; c < 4; c++) oa[mb].e[c] *= al;

        // ---- PV: O^T[d][q] += Vt.P  (P round-trip is wave-private: no barrier) ----
#pragma unroll
        for (int ks = 0; ks < 2; ks++) {
            s16x8 pf = *(const s16x8*)&QPs[(wv * 16 + l15) * STR + ks * 32 + quad * 8];
#pragma unroll
            for (int mb = 0; mb < 4; mb++) {
                int d = mb * 16 + l15;
                int col = (((ks * 4 + quad) ^ (d >> 3)) << 3);
                s16x8 vf = *(const s16x8*)&Vt[d * STR + col];
                oa[mb].v = __builtin_amdgcn_mfma_f32_16x16x32_bf16(vf, pf, oa[mb].v, 0, 0, 0);
            }
        }
    }

    // ---- epilogue ----
    float rl = 1.0f / lsum;
    int qrow = qs + wv * 16 + l15;
    float* orow = outg + ((size_t)bh * SQ + qrow) * DH;
#pragma unroll
    for (int mb = 0; mb < 4; mb++) {
        int d0 = mb * 16 + quad * 4;
        *(float4*)(orow + d0) = make_float4(oa[mb].e[0] * rl, oa[mb].e[1] * rl,
                                            oa[mb].e[2] * rl, oa[mb].e[3] * rl);
    }
}

extern "C" void kernel_launch(void* const* d_in, const int* in_sizes, int n_in,
                              void* d_out, int out_size, void* d_ws, size_t ws_size,
                              hipStream_t stream) {
    const float* q   = (const float*)d_in[0];
    const float* k   = (const float*)d_in[1];
    const float* v   = (const float*)d_in[2];
    const float* rot = (const float*)d_in[3];
    float* out = (float*)d_out;

    char* w = (char*)d_ws;
    const size_t tab_bytes = (size_t)SQ * DH * sizeof(float2);        // 1 MiB
    const size_t q_bytes   = (size_t)NBH * SQ * DH * sizeof(u16);     // 8 MiB
    const size_t k_bytes   = (size_t)NKV * SQ * DH * sizeof(u16);     // 2 MiB
    const size_t v_bytes   = k_bytes;                                 // 2 MiB
    float2* tab = (float2*)w;
    u16* qp = (u16*)(w + tab_bytes);
    u16* kp = (u16*)(w + tab_bytes + q_bytes);
    u16* vp = (u16*)(w + tab_bytes + q_bytes + k_bytes);
    int use_tab = (ws_size >= tab_bytes) ? 1 : 0;
    int use_pre = (ws_size >= tab_bytes + q_bytes + k_bytes + v_bytes) ? 1 : 0;

    if (use_tab)
        hipLaunchKernelGGL(sincos_kernel, dim3((SQ * DH + 255) / 256), dim3(256), 0, stream,
                           rot, tab);
    if (use_pre)
        hipLaunchKernelGGL(prep_kernel, dim3((RQ + RK + RV) / 4), dim3(256), 0, stream,
                           q, k, v, tab, qp, kp, vp);

    hipLaunchKernelGGL(attn_kernel, dim3(32, NBH), dim3(256), 0, stream,
                       q, k, v, rot, tab, use_tab, use_pre, qp, kp, vp, out);
}

// Round 7
// 161.925 us; speedup vs baseline: 10.9423x; 1.3388x over previous
//
#include <hip/hip_runtime.h>
#include <stdint.h>

typedef unsigned short u16;
typedef short s16x8 __attribute__((ext_vector_type(8)));
typedef float f32x4 __attribute__((ext_vector_type(4)));

#define SQ 2048
#define DH 64
#define BM 64
#define BN 64
#define STR 72             // LDS row stride in shorts (144 B, 16B-multiple)
#define SPECIAL_START 2040
#define NBH 32             // b*h
#define NKV 8              // b*hk
#define CSHIFT 25.0f       // constant softmax shift (any constant is exact)

union U8 { s16x8 v; short e[8]; };
union F4 { f32x4 v; float e[4]; };

__device__ __forceinline__ u16 f2bf(float x) {  // round-to-nearest-even
    uint32_t u = __float_as_uint(x);
    return (u16)((u + 0x7fffu + ((u >> 16) & 1u)) >> 16);
}

__global__ void sincos_kernel(const float* __restrict__ rot, float2* __restrict__ tab) {
    int i = blockIdx.x * 256 + threadIdx.x;
    if (i >= SQ * DH) return;
    float s, c;
    sincosf(rot[i], &s, &c);
    tab[i] = make_float2(c, s);
}

// ---- merged prep: V tiles (LDS transpose+swizzle) + Q/K rope rows ----
#define VTILES (NKV * 32)                 // 256 tile-blocks
#define RQ (NBH * SQ)
#define RK (NKV * SQ)
#define QKBLK ((RQ + RK) / 32)            // 2560 row-blocks (32 rows each)
__global__ __launch_bounds__(256)
void prep_kernel(const float* __restrict__ qg, const float* __restrict__ kg,
                 const float* __restrict__ vg, const float2* __restrict__ tab,
                 u16* __restrict__ qp, u16* __restrict__ kp, u16* __restrict__ vp)
{
    const int tid = threadIdx.x;
    if (blockIdx.x < VTILES) {
        // --- V: one 64x64 tile, transpose+XOR-swizzle through LDS ---
        __shared__ short Vls[64 * STR];
        const int tile = blockIdx.x;                   // bkv*32 + kt
        const float* src = vg + ((size_t)(tile >> 5) * SQ + (size_t)(tile & 31) * 64) * DH;
        {
            int kv = tid >> 2, c0 = (tid & 3) * 16;
            const float* s4 = src + (size_t)kv * DH + c0;
            U8 w0, w1;
#pragma unroll
            for (int t = 0; t < 2; t++) {
                float4 f0 = *(const float4*)(s4 + t * 8);
                float4 f1 = *(const float4*)(s4 + t * 8 + 4);
                U8& w = t ? w1 : w0;
                w.e[0] = (short)f2bf(f0.x); w.e[1] = (short)f2bf(f0.y);
                w.e[2] = (short)f2bf(f0.z); w.e[3] = (short)f2bf(f0.w);
                w.e[4] = (short)f2bf(f1.x); w.e[5] = (short)f2bf(f1.y);
                w.e[6] = (short)f2bf(f1.z); w.e[7] = (short)f2bf(f1.w);
            }
            *(s16x8*)&Vls[kv * STR + c0]     = w0.v;
            *(s16x8*)&Vls[kv * STR + c0 + 8] = w1.v;
        }
        __syncthreads();
        {
            int d = tid >> 2, c0 = (tid & 3) * 16;
            U8 o0, o1;
#pragma unroll
            for (int j = 0; j < 16; j++) {
                int col = c0 + j;
                int kv = (((col >> 3) ^ (d >> 3)) << 3) | (col & 7);
                (j < 8 ? o0 : o1).e[j & 7] = Vls[kv * STR + d];
            }
            u16* dst = vp + (((size_t)tile * 64 + d) << 6) + c0;
            *(s16x8*)dst       = o0.v;
            *(s16x8*)(dst + 8) = o1.v;
        }
    } else {
        // --- Q/K rope: 32 rows per block, 8 elems per thread ---
        int bx = blockIdx.x - VTILES;
        int r8 = tid >> 3, c0 = (tid & 7) * 4;
        int R = bx * 32 + r8;
        const int isQ = (R < RQ);
        const int r = isQ ? R : R - RQ;
        const int s = r & (SQ - 1);
        const float* src = (isQ ? qg : kg) + (size_t)r * DH;
        u16*         dst = (isQ ? qp : kp) + (size_t)r * DH;
        float4 a = *(const float4*)(src + c0);
        float4 b = *(const float4*)(src + c0 + 32);
        float4 t0 = *(const float4*)&tab[(size_t)s * DH + c0];      // (cs0,sn0,cs1,sn1)
        float4 t1 = *(const float4*)&tab[(size_t)s * DH + c0 + 2];  // (cs2,sn2,cs3,sn3)
        u16 lo[4], hi[4];
        lo[0] = f2bf(a.x * t0.x - b.x * t0.y); hi[0] = f2bf(b.x * t0.x + a.x * t0.y);
        lo[1] = f2bf(a.y * t0.z - b.y * t0.w); hi[1] = f2bf(b.y * t0.z + a.y * t0.w);
        lo[2] = f2bf(a.z * t1.x - b.z * t1.y); hi[2] = f2bf(b.z * t1.x + a.z * t1.y);
        lo[3] = f2bf(a.w * t1.z - b.w * t1.w); hi[3] = f2bf(b.w * t1.z + a.w * t1.w);
        *(uint2*)(dst + c0)      = *(uint2*)lo;
        *(uint2*)(dst + c0 + 32) = *(uint2*)hi;
    }
}

__device__ __forceinline__ void getcs(const float2* tab, int use_tab,
                                      const float* rotg, int srow, int c,
                                      float& cs, float& sn) {
    if (use_tab) { float2 t = tab[(size_t)srow * DH + c]; cs = t.x; sn = t.y; }
    else          { sincosf(rotg[(size_t)srow * DH + c], &sn, &cs); }
}

// S^T = K.Q^T via mfma(A=K,B=Q)   -> C: col(l15)=q, row(quad*4+c)=kv
// O^T = V^T.P via mfma(A=Vt,B=P)  -> C: col(l15)=q, row(quad*4+c)=d
__global__ __launch_bounds__(256, 5)
void attn_kernel(const float* __restrict__ qg, const float* __restrict__ kg,
                 const float* __restrict__ vg, const float* __restrict__ rotg,
                 const float2* __restrict__ tab, int use_tab, int use_pre,
                 const u16* __restrict__ qp, const u16* __restrict__ kp,
                 const u16* __restrict__ vp, float* __restrict__ outg)
{
    const int x  = blockIdx.x;
    const int qt = (x & 1) ? (31 - (x >> 1)) : (x >> 1);  // heavy+light pairing
    const int bh = blockIdx.y;
    const int bb = bh >> 4, hh = bh & 15;
    const int bkv = bb * 4 + (hh >> 2);
    const int qs = qt * BM;

    const int tid = threadIdx.x;
    const int wv = tid >> 6, lane = tid & 63;
    const int l15 = lane & 15, quad = lane >> 4;

    __shared__ __align__(16) short QPs[BM * STR];  // Q tile, then P[q][kv] (wave-private rows)
    __shared__ __align__(16) short Ks[BN * STR];
    __shared__ __align__(16) short Vt[DH * STR];   // [d][kv-swizzled]

    const size_t qbase  = ((size_t)bh * SQ + qs) * DH;
    const size_t kvbase = ((size_t)bkv * SQ) * DH;

    // ---- stage Q tile ----
    if (use_pre) {
        int r = tid >> 2, c0 = (tid & 3) * 16;
        const u16* src = qp + qbase + (size_t)r * DH + c0;
        *(s16x8*)&QPs[r * STR + c0]     = *(const s16x8*)src;
        *(s16x8*)&QPs[r * STR + c0 + 8] = *(const s16x8*)(src + 8);
    } else {
        int r = tid >> 2, c0 = (tid & 3) * 8;
        int srow = qs + r;
        const float* gq = qg + qbase + (size_t)r * DH;
        float a[8], b[8];
        *(float4*)&a[0] = *(const float4*)(gq + c0);
        *(float4*)&a[4] = *(const float4*)(gq + c0 + 4);
        *(float4*)&b[0] = *(const float4*)(gq + c0 + 32);
        *(float4*)&b[4] = *(const float4*)(gq + c0 + 36);
        U8 o0, o1;
#pragma unroll
        for (int j = 0; j < 8; j++) {
            float cs, sn;
            getcs(tab, use_tab, rotg, srow, c0 + j, cs, sn);
            o0.e[j] = (short)f2bf(a[j] * cs - b[j] * sn);
            o1.e[j] = (short)f2bf(b[j] * cs + a[j] * sn);
        }
        *(s16x8*)&QPs[r * STR + c0]      = o0.v;
        *(s16x8*)&QPs[r * STR + c0 + 32] = o1.v;
    }
    __syncthreads();

    // ---- preload Q fragments: B[n=q(l15)][k=quad*8+j] ----
    s16x8 qf[2];
#pragma unroll
    for (int ks = 0; ks < 2; ks++)
        qf[ks] = *(const s16x8*)&QPs[(wv * 16 + l15) * STR + ks * 32 + quad * 8];

    F4 oa[4];
#pragma unroll
    for (int mb = 0; mb < 4; mb++) oa[mb].v = (f32x4){0.f, 0.f, 0.f, 0.f};
    float lsum = 0.f;

    const int nkt = (qt / 4 + 1) * 4;   // block-causal: tiles fully allowed
    const int qglob = qs + wv * 16 + l15;

    for (int kt = 0; kt < nkt; kt++) {
        __syncthreads();   // prev iteration's Ks/Vt reads done

        if (use_pre) {
            int r = tid >> 2, c0 = (tid & 3) * 16;
            const u16* srck = kp + kvbase + (size_t)(kt * BN + r) * DH + c0;
            *(s16x8*)&Ks[r * STR + c0]     = *(const s16x8*)srck;
            *(s16x8*)&Ks[r * STR + c0 + 8] = *(const s16x8*)(srck + 8);
            const u16* srcv = vp + (((size_t)(bkv * 32 + kt) * 64 + r) << 6) + c0;
            *(s16x8*)&Vt[r * STR + c0]     = *(const s16x8*)srcv;
            *(s16x8*)&Vt[r * STR + c0 + 8] = *(const s16x8*)(srcv + 8);
        } else {
            {   // K rope inline
                int r = tid >> 2, c0 = (tid & 3) * 8;
                int srow = kt * BN + r;
                const float* gk = kg + kvbase + (size_t)srow * DH;
                float a[8], b[8];
                *(float4*)&a[0] = *(const float4*)(gk + c0);
                *(float4*)&a[4] = *(const float4*)(gk + c0 + 4);
                *(float4*)&b[0] = *(const float4*)(gk + c0 + 32);
                *(float4*)&b[4] = *(const float4*)(gk + c0 + 36);
                U8 o0, o1;
#pragma unroll
                for (int j = 0; j < 8; j++) {
                    float cs, sn;
                    getcs(tab, use_tab, rotg, srow, c0 + j, cs, sn);
                    o0.e[j] = (short)f2bf(a[j] * cs - b[j] * sn);
                    o1.e[j] = (short)f2bf(b[j] * cs + a[j] * sn);
                }
                *(s16x8*)&Ks[r * STR + c0]      = o0.v;
                *(s16x8*)&Ks[r * STR + c0 + 32] = o1.v;
            }
            {   // V transpose+swizzle inline (scalar scatter, fallback only)
                int r = tid >> 2, c0 = (tid & 3) * 16;
                const float* gv = vg + kvbase + (size_t)(kt * BN + r) * DH;
                float vv[16];
#pragma unroll
                for (int t = 0; t < 4; t++)
                    *(float4*)&vv[t * 4] = *(const float4*)(gv + c0 + t * 4);
#pragma unroll
                for (int j = 0; j < 16; j++) {
                    int d = c0 + j;
                    int col = (((r >> 3) ^ (d >> 3)) << 3) | (r & 7);
                    Vt[d * STR + col] = (short)f2bf(vv[j]);
                }
            }
        }
        __syncthreads();

        // ---- QK^T: S^T[kv][q] ----
        F4 sa[4];
#pragma unroll
        for (int mb = 0; mb < 4; mb++) sa[mb].v = (f32x4){0.f, 0.f, 0.f, 0.f};
#pragma unroll
        for (int ks = 0; ks < 2; ks++) {
#pragma unroll
            for (int mb = 0; mb < 4; mb++) {
                s16x8 kf = *(const s16x8*)&Ks[(mb * 16 + l15) * STR + ks * 32 + quad * 8];
                sa[mb].v = __builtin_amdgcn_mfma_f32_16x16x32_bf16(kf, qf[ks], sa[mb].v, 0, 0, 0);
            }
        }

        // ---- softclamp (poly tanh) + constant-shift softmax ----
        F4 pa[4];
#pragma unroll
        for (int mb = 0; mb < 4; mb++)
#pragma unroll
            for (int c = 0; c < 4; c++) {
                float sim = sa[mb].e[c] * 0.125f;
                // 50*tanh(sim/50) = sim*(1 + u2*(-1/3 + u2*(2/15))), u=sim/50
                float u  = sim * 0.02f;
                float u2 = u * u;
                float poly = fmaf(u2, fmaf(u2, 2.f / 15.f, -1.f / 3.f), 1.f);
                float yy = sim * poly;
                pa[mb].e[c] = __expf(yy - CSHIFT);
            }
        if (kt == 31) {   // only tile containing special keys
            if (qglob < SPECIAL_START) {
#pragma unroll
                for (int mb = 0; mb < 4; mb++)
#pragma unroll
                    for (int c = 0; c < 4; c++) {
                        int kvglob = kt * BN + mb * 16 + quad * 4 + c;
                        if (kvglob >= SPECIAL_START) pa[mb].e[c] = 0.f;
                    }
            }
        }
        short* prow = &QPs[(wv * 16 + l15) * STR];
#pragma unroll
        for (int mb = 0; mb < 4; mb++) {
            U8 pk;
#pragma unroll
            for (int c = 0; c < 4; c++) {
                float p = pa[mb].e[c];
                lsum += p;
                pk.e[c] = (short)f2bf(p);
            }
            *(short4*)&prow[mb * 16 + quad * 4] = make_short4(pk.e[0], pk.e[1], pk.e[2], pk.e[3]);
        }

        // ---- PV: O^T[d][q] += Vt.P  (P round-trip wave-private: no barrier) ----
#pragma unroll
        for (int ks = 0; ks < 2; ks++) {
            s16x8 pf = *(const s16x8*)&QPs[(wv * 16 + l15) * STR + ks * 32 + quad * 8];
#pragma unroll
            for (int mb = 0; mb < 4; mb++) {
                int d = mb * 16 + l15;
                int col = (((ks * 4 + quad) ^ (d >> 3)) << 3);
                s16x8 vf = *(const s16x8*)&Vt[d * STR + col];
                oa[mb].v = __builtin_amdgcn_mfma_f32_16x16x32_bf16(vf, pf, oa[mb].v, 0, 0, 0);
            }
        }
    }

    // ---- final lsum reduction across quads (kv partitioned by quad) ----
    lsum += __shfl_xor(lsum, 16, 64);
    lsum += __shfl_xor(lsum, 32, 64);

    // ---- epilogue ----
    float rl = 1.0f / lsum;
    int qrow = qs + wv * 16 + l15;
    float* orow = outg + ((size_t)bh * SQ + qrow) * DH;
#pragma unroll
    for (int mb = 0; mb < 4; mb++) {
        int d0 = mb * 16 + quad * 4;
        *(float4*)(orow + d0) = make_float4(oa[mb].e[0] * rl, oa[mb].e[1] * rl,
                                            oa[mb].e[2] * rl, oa[mb].e[3] * rl);
    }
}

extern "C" void kernel_launch(void* const* d_in, const int* in_sizes, int n_in,
                              void* d_out, int out_size, void* d_ws, size_t ws_size,
                              hipStream_t stream) {
    const float* q   = (const float*)d_in[0];
    const float* k   = (const float*)d_in[1];
    const float* v   = (const float*)d_in[2];
    const float* rot = (const float*)d_in[3];
    float* out = (float*)d_out;

    char* w = (char*)d_ws;
    const size_t tab_bytes = (size_t)SQ * DH * sizeof(float2);        // 1 MiB
    const size_t q_bytes   = (size_t)NBH * SQ * DH * sizeof(u16);     // 8 MiB
    const size_t k_bytes   = (size_t)NKV * SQ * DH * sizeof(u16);     // 2 MiB
    const size_t v_bytes   = k_bytes;                                 // 2 MiB
    float2* tab = (float2*)w;
    u16* qp = (u16*)(w + tab_bytes);
    u16* kp = (u16*)(w + tab_bytes + q_bytes);
    u16* vp = (u16*)(w + tab_bytes + q_bytes + k_bytes);
    int use_tab = (ws_size >= tab_bytes) ? 1 : 0;
    int use_pre = (ws_size >= tab_bytes + q_bytes + k_bytes + v_bytes) ? 1 : 0;

    if (use_tab)
        hipLaunchKernelGGL(sincos_kernel, dim3((SQ * DH + 255) / 256), dim3(256), 0, stream,
                           rot, tab);
    if (use_pre)
        hipLaunchKernelGGL(prep_kernel, dim3(VTILES + QKBLK), dim3(256), 0, stream,
                           q, k, v, tab, qp, kp, vp);

    hipLaunchKernelGGL(attn_kernel, dim3(32, NBH), dim3(256), 0, stream,
                       q, k, v, rot, tab, use_tab, use_pre, qp, kp, vp, out);
}

// Round 8
// 161.629 us; speedup vs baseline: 10.9624x; 1.0018x over previous
//
#include <hip/hip_runtime.h>
#include <stdint.h>

typedef unsigned short u16;
typedef short s16x8 __attribute__((ext_vector_type(8)));
typedef float f32x4 __attribute__((ext_vector_type(4)));

#define SQ 2048
#define DH 64
#define BM 64
#define BN 64
#define STR 72             // LDS row stride in shorts (144 B, 16B-multiple)
#define SPECIAL_START 2040
#define NBH 32             // b*h
#define NKV 8              // b*hk
#define CSHIFT 25.0f       // constant softmax shift (exact for softmax)

union U8 { s16x8 v; short e[8]; };
union F4 { f32x4 v; float e[4]; };

__device__ __forceinline__ u16 f2bf(float x) {  // round-to-nearest-even
    uint32_t u = __float_as_uint(x);
    return (u16)((u + 0x7fffu + ((u >> 16) & 1u)) >> 16);
}
__device__ __forceinline__ uint32_t pkbf(float a, float b) {  // pack 2 bf16
#if __has_builtin(__builtin_amdgcn_cvt_pk_bf16_f32)
    auto t = __builtin_amdgcn_cvt_pk_bf16_f32(a, b);
    return __builtin_bit_cast(uint32_t, t);
#else
    return (uint32_t)f2bf(a) | ((uint32_t)f2bf(b) << 16);
#endif
}

// ---- prep: V tiles (LDS transpose+swizzle) + Q/K rope rows; sincos inline ----
#define VTILES (NKV * 32)                 // 256 tile-blocks
#define RQ (NBH * SQ)
#define RK (NKV * SQ)
#define QKBLK ((RQ + RK) / 32)            // 2560 row-blocks (32 rows each)
__global__ __launch_bounds__(256)
void prep_kernel(const float* __restrict__ qg, const float* __restrict__ kg,
                 const float* __restrict__ vg, const float* __restrict__ rotg,
                 u16* __restrict__ qp, u16* __restrict__ kp, u16* __restrict__ vp)
{
    const int tid = threadIdx.x;
    if (blockIdx.x < VTILES) {
        // --- V: one 64x64 tile, transpose+XOR-swizzle through LDS ---
        __shared__ short Vls[64 * STR];
        const int tile = blockIdx.x;                   // bkv*32 + kt
        const float* src = vg + ((size_t)(tile >> 5) * SQ + (size_t)(tile & 31) * 64) * DH;
        {
            int kv = tid >> 2, c0 = (tid & 3) * 16;
            const float* s4 = src + (size_t)kv * DH + c0;
            float4 f0 = *(const float4*)(s4);
            float4 f1 = *(const float4*)(s4 + 4);
            float4 f2 = *(const float4*)(s4 + 8);
            float4 f3 = *(const float4*)(s4 + 12);
            uint4 w0 = make_uint4(pkbf(f0.x, f0.y), pkbf(f0.z, f0.w),
                                  pkbf(f1.x, f1.y), pkbf(f1.z, f1.w));
            uint4 w1 = make_uint4(pkbf(f2.x, f2.y), pkbf(f2.z, f2.w),
                                  pkbf(f3.x, f3.y), pkbf(f3.z, f3.w));
            *(uint4*)&Vls[kv * STR + c0]     = w0;
            *(uint4*)&Vls[kv * STR + c0 + 8] = w1;
        }
        __syncthreads();
        {
            int d = tid >> 2, c0 = (tid & 3) * 16;
            U8 o0, o1;
#pragma unroll
            for (int j = 0; j < 16; j++) {
                int col = c0 + j;
                int kv = (((col >> 3) ^ (d >> 3)) << 3) | (col & 7);
                (j < 8 ? o0 : o1).e[j & 7] = Vls[kv * STR + d];
            }
            u16* dst = vp + (((size_t)tile * 64 + d) << 6) + c0;
            *(s16x8*)dst       = o0.v;
            *(s16x8*)(dst + 8) = o1.v;
        }
    } else {
        // --- Q/K rope: 32 rows per block, 8 elems per thread; sincos inline ---
        int bx = blockIdx.x - VTILES;
        int r8 = tid >> 3, c0 = (tid & 7) * 4;      // c0 in 0..28 (<32)
        int R = bx * 32 + r8;
        const int isQ = (R < RQ);
        const int r = isQ ? R : R - RQ;
        const int s = r & (SQ - 1);
        const float* src = (isQ ? qg : kg) + (size_t)r * DH;
        u16*         dst = (isQ ? qp : kp) + (size_t)r * DH;
        float4 a  = *(const float4*)(src + c0);
        float4 b  = *(const float4*)(src + c0 + 32);
        float4 rv = *(const float4*)(rotg + (size_t)s * DH + c0);
        float cs0, sn0, cs1, sn1, cs2, sn2, cs3, sn3;
        sincosf(rv.x, &sn0, &cs0);
        sincosf(rv.y, &sn1, &cs1);
        sincosf(rv.z, &sn2, &cs2);
        sincosf(rv.w, &sn3, &cs3);
        float lo0 = a.x * cs0 - b.x * sn0, hi0 = b.x * cs0 + a.x * sn0;
        float lo1 = a.y * cs1 - b.y * sn1, hi1 = b.y * cs1 + a.y * sn1;
        float lo2 = a.z * cs2 - b.z * sn2, hi2 = b.z * cs2 + a.z * sn2;
        float lo3 = a.w * cs3 - b.w * sn3, hi3 = b.w * cs3 + a.w * sn3;
        *(uint2*)(dst + c0)      = make_uint2(pkbf(lo0, lo1), pkbf(lo2, lo3));
        *(uint2*)(dst + c0 + 32) = make_uint2(pkbf(hi0, hi1), pkbf(hi2, hi3));
    }
}

// S^T = K.Q^T via mfma(A=K,B=Q)   -> C: col(l15)=q, row(quad*4+c)=kv
// O^T = V^T.P via mfma(A=Vt,B=P)  -> C: col(l15)=q, row(quad*4+c)=d
__global__ __launch_bounds__(256, 4)
void attn_kernel(const float* __restrict__ qg, const float* __restrict__ kg,
                 const float* __restrict__ vg, const float* __restrict__ rotg,
                 int use_pre,
                 const u16* __restrict__ qp, const u16* __restrict__ kp,
                 const u16* __restrict__ vp, float* __restrict__ outg)
{
    const int x  = blockIdx.x;
    const int qt = (x & 1) ? (31 - (x >> 1)) : (x >> 1);  // heavy+light pairing
    const int bh = blockIdx.y;
    const int bb = bh >> 4, hh = bh & 15;
    const int bkv = bb * 4 + (hh >> 2);
    const int qs = qt * BM;

    const int tid = threadIdx.x;
    const int wv = tid >> 6, lane = tid & 63;
    const int l15 = lane & 15, quad = lane >> 4;

    __shared__ __align__(16) short QPs[BM * STR];  // Q tile, then P[q][kv] (wave-private rows)
    __shared__ __align__(16) short Ks[BN * STR];
    __shared__ __align__(16) short Vt[DH * STR];   // [d][kv-swizzled]

    const size_t qbase  = ((size_t)bh * SQ + qs) * DH;
    const size_t kvbase = ((size_t)bkv * SQ) * DH;

    const int nkt = (qt / 4 + 1) * 4;   // block-causal: tiles fully allowed
    const int qglob = qs + wv * 16 + l15;

    // ---- K/V register prefetch (use_pre path) ----
    const int r4 = tid >> 2, c16 = (tid & 3) * 16;
    s16x8 kpr0, kpr1, vpr0, vpr1;
    auto pref = [&](int kt) {
        const u16* srck = kp + kvbase + (size_t)(kt * BN + r4) * DH + c16;
        kpr0 = *(const s16x8*)srck;
        kpr1 = *(const s16x8*)(srck + 8);
        const u16* srcv = vp + (((size_t)(bkv * 32 + kt) * 64 + r4) << 6) + c16;
        vpr0 = *(const s16x8*)srcv;
        vpr1 = *(const s16x8*)(srcv + 8);
    };
    if (use_pre) pref(0);

    // ---- stage Q tile ----
    if (use_pre) {
        const u16* src = qp + qbase + (size_t)r4 * DH + c16;
        *(s16x8*)&QPs[r4 * STR + c16]     = *(const s16x8*)src;
        *(s16x8*)&QPs[r4 * STR + c16 + 8] = *(const s16x8*)(src + 8);
    } else {
        int r = tid >> 2, c0 = (tid & 3) * 8;
        int srow = qs + r;
        const float* gq = qg + qbase + (size_t)r * DH;
        float a[8], b[8];
        *(float4*)&a[0] = *(const float4*)(gq + c0);
        *(float4*)&a[4] = *(const float4*)(gq + c0 + 4);
        *(float4*)&b[0] = *(const float4*)(gq + c0 + 32);
        *(float4*)&b[4] = *(const float4*)(gq + c0 + 36);
        U8 o0, o1;
#pragma unroll
        for (int j = 0; j < 8; j++) {
            float cs, sn;
            sincosf(rotg[(size_t)srow * DH + ((c0 + j) & 31)], &sn, &cs);
            o0.e[j] = (short)f2bf(a[j] * cs - b[j] * sn);
            o1.e[j] = (short)f2bf(b[j] * cs + a[j] * sn);
        }
        *(s16x8*)&QPs[r * STR + c0]      = o0.v;
        *(s16x8*)&QPs[r * STR + c0 + 32] = o1.v;
    }
    __syncthreads();

    // ---- preload Q fragments: B[n=q(l15)][k=quad*8+j] ----
    s16x8 qf[2];
#pragma unroll
    for (int ks = 0; ks < 2; ks++)
        qf[ks] = *(const s16x8*)&QPs[(wv * 16 + l15) * STR + ks * 32 + quad * 8];

    F4 oa[4];
#pragma unroll
    for (int mb = 0; mb < 4; mb++) oa[mb].v = (f32x4){0.f, 0.f, 0.f, 0.f};
    float lsum = 0.f;

    for (int kt = 0; kt < nkt; kt++) {
        __syncthreads();   // prev iteration's Ks/Vt reads done

        if (use_pre) {
            // LDS write from prefetch registers (no vmcnt wait here)
            *(s16x8*)&Ks[r4 * STR + c16]     = kpr0;
            *(s16x8*)&Ks[r4 * STR + c16 + 8] = kpr1;
            *(s16x8*)&Vt[r4 * STR + c16]     = vpr0;
            *(s16x8*)&Vt[r4 * STR + c16 + 8] = vpr1;
        } else {
            {   // K rope inline (fallback)
                int r = tid >> 2, c0 = (tid & 3) * 8;
                int srow = kt * BN + r;
                const float* gk = kg + kvbase + (size_t)srow * DH;
                float a[8], b[8];
                *(float4*)&a[0] = *(const float4*)(gk + c0);
                *(float4*)&a[4] = *(const float4*)(gk + c0 + 4);
                *(float4*)&b[0] = *(const float4*)(gk + c0 + 32);
                *(float4*)&b[4] = *(const float4*)(gk + c0 + 36);
                U8 o0, o1;
#pragma unroll
                for (int j = 0; j < 8; j++) {
                    float cs, sn;
                    sincosf(rotg[(size_t)srow * DH + ((c0 + j) & 31)], &sn, &cs);
                    o0.e[j] = (short)f2bf(a[j] * cs - b[j] * sn);
                    o1.e[j] = (short)f2bf(b[j] * cs + a[j] * sn);
                }
                *(s16x8*)&Ks[r * STR + c0]      = o0.v;
                *(s16x8*)&Ks[r * STR + c0 + 32] = o1.v;
            }
            {   // V transpose+swizzle inline (fallback)
                int r = tid >> 2, c0 = (tid & 3) * 16;
                const float* gv = vg + kvbase + (size_t)(kt * BN + r) * DH;
                float vv[16];
#pragma unroll
                for (int t = 0; t < 4; t++)
                    *(float4*)&vv[t * 4] = *(const float4*)(gv + c0 + t * 4);
#pragma unroll
                for (int j = 0; j < 16; j++) {
                    int d = c0 + j;
                    int col = (((r >> 3) ^ (d >> 3)) << 3) | (r & 7);
                    Vt[d * STR + col] = (short)f2bf(vv[j]);
                }
            }
        }
        __syncthreads();

        // issue next tile's global loads NOW; latency overlaps compute below
        if (use_pre && (kt + 1 < nkt)) pref(kt + 1);

        // ---- QK^T: S^T[kv][q] ----
        F4 sa[4];
#pragma unroll
        for (int mb = 0; mb < 4; mb++) sa[mb].v = (f32x4){0.f, 0.f, 0.f, 0.f};
#pragma unroll
        for (int ks = 0; ks < 2; ks++) {
#pragma unroll
            for (int mb = 0; mb < 4; mb++) {
                s16x8 kf = *(const s16x8*)&Ks[(mb * 16 + l15) * STR + ks * 32 + quad * 8];
                sa[mb].v = __builtin_amdgcn_mfma_f32_16x16x32_bf16(kf, qf[ks], sa[mb].v, 0, 0, 0);
            }
        }

        // ---- softclamp (poly tanh) + constant-shift softmax ----
        F4 pa[4];
#pragma unroll
        for (int mb = 0; mb < 4; mb++)
#pragma unroll
            for (int c = 0; c < 4; c++) {
                float sim = sa[mb].e[c] * 0.125f;
                float u  = sim * 0.02f;
                float u2 = u * u;
                float poly = fmaf(u2, fmaf(u2, 2.f / 15.f, -1.f / 3.f), 1.f);
                float yy = sim * poly;          // 50*tanh(sim/50)
                pa[mb].e[c] = __expf(yy - CSHIFT);
            }
        if (kt == 31 && qglob < SPECIAL_START) {
#pragma unroll
            for (int mb = 0; mb < 4; mb++)
#pragma unroll
                for (int c = 0; c < 4; c++) {
                    int kvglob = kt * BN + mb * 16 + quad * 4 + c;
                    if (kvglob >= SPECIAL_START) pa[mb].e[c] = 0.f;
                }
        }
        short* prow = &QPs[(wv * 16 + l15) * STR];
#pragma unroll
        for (int mb = 0; mb < 4; mb++) {
            lsum += pa[mb].e[0] + pa[mb].e[1] + pa[mb].e[2] + pa[mb].e[3];
            uint2 pw = make_uint2(pkbf(pa[mb].e[0], pa[mb].e[1]),
                                  pkbf(pa[mb].e[2], pa[mb].e[3]));
            *(uint2*)&prow[mb * 16 + quad * 4] = pw;   // 8B-aligned b64 store
        }

        // ---- PV: O^T[d][q] += Vt.P  (P round-trip wave-private: no barrier) ----
#pragma unroll
        for (int ks = 0; ks < 2; ks++) {
            s16x8 pf = *(const s16x8*)&QPs[(wv * 16 + l15) * STR + ks * 32 + quad * 8];
#pragma unroll
            for (int mb = 0; mb < 4; mb++) {
                int d = mb * 16 + l15;
                int col = (((ks * 4 + quad) ^ (d >> 3)) << 3);
                s16x8 vf = *(const s16x8*)&Vt[d * STR + col];
                oa[mb].v = __builtin_amdgcn_mfma_f32_16x16x32_bf16(vf, pf, oa[mb].v, 0, 0, 0);
            }
        }
    }

    // ---- final lsum reduction across quads (kv partitioned by quad) ----
    lsum += __shfl_xor(lsum, 16, 64);
    lsum += __shfl_xor(lsum, 32, 64);

    // ---- epilogue ----
    float rl = 1.0f / lsum;
    int qrow = qs + wv * 16 + l15;
    float* orow = outg + ((size_t)bh * SQ + qrow) * DH;
#pragma unroll
    for (int mb = 0; mb < 4; mb++) {
        int d0 = mb * 16 + quad * 4;
        *(float4*)(orow + d0) = make_float4(oa[mb].e[0] * rl, oa[mb].e[1] * rl,
                                            oa[mb].e[2] * rl, oa[mb].e[3] * rl);
    }
}

extern "C" void kernel_launch(void* const* d_in, const int* in_sizes, int n_in,
                              void* d_out, int out_size, void* d_ws, size_t ws_size,
                              hipStream_t stream) {
    const float* q   = (const float*)d_in[0];
    const float* k   = (const float*)d_in[1];
    const float* v   = (const float*)d_in[2];
    const float* rot = (const float*)d_in[3];
    float* out = (float*)d_out;

    char* w = (char*)d_ws;
    const size_t q_bytes = (size_t)NBH * SQ * DH * sizeof(u16);     // 8 MiB
    const size_t k_bytes = (size_t)NKV * SQ * DH * sizeof(u16);     // 2 MiB
    const size_t v_bytes = k_bytes;                                 // 2 MiB
    u16* qp = (u16*)w;
    u16* kp = (u16*)(w + q_bytes);
    u16* vp = (u16*)(w + q_bytes + k_bytes);
    int use_pre = (ws_size >= q_bytes + k_bytes + v_bytes) ? 1 : 0;

    if (use_pre)
        hipLaunchKernelGGL(prep_kernel, dim3(VTILES + QKBLK), dim3(256), 0, stream,
                           q, k, v, rot, qp, kp, vp);

    hipLaunchKernelGGL(attn_kernel, dim3(32, NBH), dim3(256), 0, stream,
                       q, k, v, rot, use_pre, qp, kp, vp, out);
}